// Round 4
// baseline (54.587 us; speedup 1.0000x reference)
//
#include <hip/hip_runtime.h>

typedef __bf16 v8bf __attribute__((ext_vector_type(8)));
typedef float f32x4 __attribute__((ext_vector_type(4)));
typedef unsigned short u16x8 __attribute__((ext_vector_type(8)));

#define C_IN 256
#define HW   64
#define OHW  63
#define NOC  128

// Wf: [kp(4)][khkw(4)][cblk(32)][oc(128)][j(8)] bf16, 1 MiB. Coalesced.
__global__ void wprep(const float* __restrict__ w, __bf16* __restrict__ Wf) {
  int f = blockIdx.x;                 // 512 filters
  int c = threadIdx.x;                // 256 channels
  f32x4 v = *(const f32x4*)(w + (size_t)f * 1024 + c * 4);  // 4 khkw taps
  int oc = f >> 2, kp = f & 3;
#pragma unroll
  for (int khkw = 0; khkw < 4; ++khkw)
    Wf[(((size_t)(kp * 4 + khkw) * 32 + (c >> 3)) * 128 + oc) * 8 + (c & 7)] =
        (__bf16)v[khkw];
}

// Block: n x (4 out rows) x (64 w) x 128 oc, 1024 thr (16 waves, 4/SIMD).
// wave = ocg(4: 32 oc) x kp(4).  acc: 2 oc-frags x 4 px-frags.
// LDS x tile: [dy(5)][wq(17)][slot(16)] 16B slots; slot(wcol,oct) =
//   (ws&1)*8 + (((ws>>1)*4 + oct) ^ (wq&7)),  wq=wcol>>2, ws=wcol&3.
// Conflict-free for both b128 writes (64 consecutive wcol) and b128 B-reads
// (16 lanes, wcol stride 2). wq=16 row = zero pad (wcol 64).
__global__ __launch_bounds__(1024, 4) void robin_main(
    const float* __restrict__ x, const __bf16* __restrict__ Wf,
    const float* __restrict__ bias, float* __restrict__ out) {
  __shared__ __align__(16) char xs[2][5 * 17 * 16 * 16];  // 2 x 21760 B
  char* xb0 = xs[0];
  char* xb1 = xs[1];

  const int tid  = threadIdx.x;
  const int lane = tid & 63;
  const int wid  = tid >> 6;
  const int hb   = blockIdx.x;       // 16
  const int n    = blockIdx.y;       // 16
  const int h0   = hb * 4;

  const int ocg  = wid >> 2;         // 0..3 -> 32 oc each
  const int kp   = wid & 3;          // parity class
  const int ph   = kp >> 1, pw = kp & 1;
  const int lcol = lane & 15;        // pixel col (B) / oc row (A)
  const int lg   = lane >> 4;        // k-octet group

  // zero-fill the wq=16 pad row (wcol 64) of both buffers
  if (tid < 20) {
    u16x8 z = {};
    *(u16x8*)(xb0 + (((tid >> 2) * 17 + 16) * 16 + (tid & 3)) * 16) = z;
  }
  if (tid >= 64 && tid < 84) {
    int idx = tid - 64;
    u16x8 z = {};
    *(u16x8*)(xb1 + (((idx >> 2) * 17 + 16) * 16 + (idx & 3)) * 16) = z;
  }

  // chunk-invariant B-frag base offsets (hh -> +2048, r -> +8704)
  int boff[4];
#pragma unroll
  for (int khkw = 0; khkw < 4; ++khkw) {
    int kh = khkw >> 1, kw = khkw & 1;
    int dy0  = ph + kh;
    int wcol = 2 * lcol + pw + kw;       // hh=0 variant
    int wq = wcol >> 2, ws = wcol & 3;
    int slot = (ws & 1) * 8 + ((((ws >> 1) << 2) + lg) ^ (wq & 7));
    boff[khkw] = ((dy0 * 17 + wq) * 16 + slot) * 16;
  }

  f32x4 acc[2][4];
#pragma unroll
  for (int m = 0; m < 2; ++m)
#pragma unroll
    for (int f = 0; f < 4; ++f) acc[m][f] = (f32x4){0.f, 0.f, 0.f, 0.f};

  const float* xbase = x + (size_t)n * C_IN * HW * HW;
  float xr0[8], xr1[8];

  // staging decomposition: unit = 8 channels at one (dy, wcol)
  // k0 (all 1024 thr): t=tid>>6: oct=t&3, dy=t>>2 (0..3), wcol=tid&63
  // k1 (tid<256):      dy=4, oct=(tid>>6)&3, wcol=tid&63
  const int s_oct0 = (tid >> 6) & 3;
  const int s_dy0  = tid >> 8;
  const int s_wcol = tid & 63;

#define LOADQ(QQ)                                                              \
  {                                                                            \
    const int c0 = (QQ) * 32;                                                  \
    {                                                                          \
      int y = h0 + s_dy0;                                                      \
      const float* p =                                                         \
          xbase + (size_t)(c0 + s_oct0 * 8) * 4096 + y * 64 + s_wcol;          \
      _Pragma("unroll") for (int j = 0; j < 8; ++j) xr0[j] = p[j * 4096];      \
    }                                                                          \
    if (tid < 256) {                                                           \
      int y = h0 + 4;                                                          \
      bool v = y < HW;                                                         \
      const float* p =                                                         \
          xbase + (size_t)(c0 + s_oct0 * 8) * 4096 + (v ? y : 63) * 64 + s_wcol;\
      _Pragma("unroll") for (int j = 0; j < 8; ++j)                            \
          xr1[j] = v ? p[j * 4096] : 0.f;                                      \
    }                                                                          \
  }

#define WRITEQ(QQ)                                                             \
  {                                                                            \
    char* xd = ((QQ) & 1) ? xb1 : xb0;                                         \
    int wq = s_wcol >> 2, ws = s_wcol & 3;                                     \
    {                                                                          \
      int slot = (ws & 1) * 8 + ((((ws >> 1) << 2) + s_oct0) ^ (wq & 7));      \
      u16x8 pk;                                                                \
      _Pragma("unroll") for (int j = 0; j < 8; ++j)                            \
          pk[j] = __builtin_bit_cast(unsigned short, (__bf16)xr0[j]);          \
      *(u16x8*)(xd + ((s_dy0 * 17 + wq) * 16 + slot) * 16) = pk;               \
    }                                                                          \
    if (tid < 256) {                                                           \
      int slot = (ws & 1) * 8 + ((((ws >> 1) << 2) + s_oct0) ^ (wq & 7));      \
      u16x8 pk;                                                                \
      _Pragma("unroll") for (int j = 0; j < 8; ++j)                            \
          pk[j] = __builtin_bit_cast(unsigned short, (__bf16)xr1[j]);          \
      *(u16x8*)(xd + ((4 * 17 + wq) * 16 + slot) * 16) = pk;                   \
    }                                                                          \
  }

  // prologue
  LOADQ(0);
  WRITEQ(0);
  __syncthreads();

  for (int q = 0; q < 8; ++q) {
    if (q < 7) LOADQ(q + 1);

    // ---- compute chunk q: 4 khkw K-steps x 8 MFMA ----
    {
      const char* xsb = (q & 1) ? xb1 : xb0;
#pragma unroll
      for (int khkw = 0; khkw < 4; ++khkw) {
        v8bf a[2];
        const __bf16* wp =
            Wf + (((size_t)(kp * 4 + khkw) * 32 + q * 4 + lg) * 128 +
                  ocg * 32 + lcol) * 8;
        a[0] = *(const v8bf*)wp;
        a[1] = *(const v8bf*)(wp + 128);

        v8bf b[4];
#pragma unroll
        for (int r = 0; r < 2; ++r)
#pragma unroll
          for (int hh = 0; hh < 2; ++hh)
            b[r * 2 + hh] =
                *(const v8bf*)(xsb + boff[khkw] + r * 8704 + hh * 2048);

#pragma unroll
        for (int m = 0; m < 2; ++m)
#pragma unroll
          for (int f = 0; f < 4; ++f)
            acc[m][f] = __builtin_amdgcn_mfma_f32_16x16x32_bf16(
                a[m], b[f], acc[m][f], 0, 0, 0);
      }
    }

    if (q < 7) {
      WRITEQ(q + 1);     // buf[(q+1)&1] free since end of iter q-1
      __syncthreads();   // writes visible before compute(q+1)
    }
  }

  // ---- epilogue: D col=lane&15 (pixel), row=(lane>>4)*4+reg (oc) ----
#pragma unroll
  for (int m = 0; m < 2; ++m) {
#pragma unroll
    for (int r = 0; r < 2; ++r) {
      const int h = h0 + 2 * r + ph;
#pragma unroll
      for (int hh = 0; hh < 2; ++hh) {
        const int w = 2 * (hh * 16 + lcol) + pw;
        f32x4 v = acc[m][r * 2 + hh];
        if (h < OHW && w < OHW) {
#pragma unroll
          for (int reg = 0; reg < 4; ++reg) {
            int oc = ocg * 32 + m * 16 + lg * 4 + reg;
            out[((size_t)(n * NOC + oc) * OHW + h) * OHW + w] =
                v[reg] + bias[oc * 4 + kp];
          }
        }
      }
    }
  }
#undef LOADQ
#undef WRITEQ
}

extern "C" void kernel_launch(void* const* d_in, const int* in_sizes, int n_in,
                              void* d_out, int out_size, void* d_ws, size_t ws_size,
                              hipStream_t stream) {
  const float* x      = (const float*)d_in[0];
  const float* weight = (const float*)d_in[1];
  const float* bias   = (const float*)d_in[2];
  float* out          = (float*)d_out;
  __bf16* Wf          = (__bf16*)d_ws;   // 1 MiB fragment-ordered weights

  wprep<<<512, 256, 0, stream>>>(weight, Wf);
  robin_main<<<dim3(16, 16), 1024, 0, stream>>>(x, Wf, bias, out);
}

// Round 5
// 44.652 us; speedup vs baseline: 1.2225x; 1.2225x over previous
//
#include <hip/hip_runtime.h>

typedef __bf16 v8bf __attribute__((ext_vector_type(8)));
typedef float f32x4 __attribute__((ext_vector_type(4)));

#define C_IN 256
#define HW   64
#define OHW  63
#define NOC  128

// Wf: [kp(4)][khkw(4)][cblk(32)][oc(128)][j(8)] bf16, 1 MiB. Coalesced.
__global__ void wprep(const float* __restrict__ w, __bf16* __restrict__ Wf) {
  int f = blockIdx.x;                 // 512 filters
  int c = threadIdx.x;                // 256 channels
  f32x4 v = *(const f32x4*)(w + (size_t)f * 1024 + c * 4);  // 4 khkw taps
  int oc = f >> 2, kp = f & 3;
#pragma unroll
  for (int khkw = 0; khkw < 4; ++khkw)
    Wf[(((size_t)(kp * 4 + khkw) * 32 + (c >> 3)) * 128 + oc) * 8 + (c & 7)] =
        (__bf16)v[khkw];
}

// Block: n x (4 out rows) x (64 w) x 128 oc, 1024 thr (16 waves, 4/SIMD).
// wave = ocg(4: 32 oc) x kp(4).  acc: 2 oc-frags x 4 px-frags.
// LDS x tile: [dy(5)][wpair(33)][par(2)][c(32)] bf16, XOR-swizzled, dbuf.
// Issue order per chunk q: A(q)->regs FIRST, then x(q+1)->regs, then compute
// (waits vmcnt only for A; x stays in flight), then WRITEQ + one barrier.
__global__ __launch_bounds__(1024, 4) void robin_main(
    const float* __restrict__ x, const __bf16* __restrict__ Wf,
    const float* __restrict__ bias, float* __restrict__ out) {
  __shared__ __align__(16) __bf16 xs[2][5 * 33 * 64];   // 2 x 21120 B
  char* xb0 = (char*)xs[0];
  char* xb1 = (char*)xs[1];

  const int tid  = threadIdx.x;
  const int lane = tid & 63;
  const int wid  = tid >> 6;
  const int hb   = blockIdx.x;       // 16
  const int n    = blockIdx.y;       // 16
  const int h0   = hb * 4;

  const int ocg  = wid >> 2;         // 0..3 -> 32 oc each
  const int kp   = wid & 3;          // parity class
  const int ph   = kp >> 1, pw = kp & 1;
  const int lcol = lane & 15;        // pixel col (B) / oc row (A)
  const int lg   = lane >> 4;        // k-octet group

  // zero-fill wpair=32 pad rows (wcol 64/65), both buffers
  if (tid < 80) {
    int g  = tid & 7;
    int t2 = tid >> 3;
    int dy = t2 % 5, bi = t2 / 5;
    f32x4 z = {0.f, 0.f, 0.f, 0.f};
    *(f32x4*)((bi ? xb1 : xb0) + (dy * 33 + 32) * 128 + g * 16) = z;
  }

  // chunk-invariant B-frag base offsets (r -> +8448, hh -> +2048; both
  // deltas touch bits >= 11, XOR swizzle touches bits 4..6 -> safe to add)
  int boff[4];
#pragma unroll
  for (int khkw = 0; khkw < 4; ++khkw) {
    int kh = khkw >> 1, kw = khkw & 1;
    int dy0  = ph + kh;
    int wcol = 2 * lcol + pw + kw;
    int wp_  = wcol >> 1;
    boff[khkw] = ((dy0 * 33 + wp_) * 128 + (wcol & 1) * 64 + lg * 16) ^
                 ((wp_ & 7) << 4);
  }

  f32x4 acc[2][4];
#pragma unroll
  for (int m = 0; m < 2; ++m)
#pragma unroll
    for (int f = 0; f < 4; ++f) acc[m][f] = (f32x4){0.f, 0.f, 0.f, 0.f};

  const float* xbase = x + (size_t)n * C_IN * HW * HW;
  f32x4 xr[3];
  v8bf  a_reg[4][2];

  // A-loads for chunk QQ: 8 dwordx4 from L2-resident Wf. MUST be issued
  // before the x-loads of LOADQ so the MFMA's vmcnt wait keeps x in flight.
#define A_LOAD(QQ)                                                             \
  {                                                                            \
    _Pragma("unroll") for (int khkw = 0; khkw < 4; ++khkw) {                   \
      const __bf16* wp =                                                       \
          Wf + (((size_t)(kp * 4 + khkw) * 32 + (QQ) * 4 + lg) * 128 +        \
                ocg * 32 + lcol) * 8;                                          \
      a_reg[khkw][0] = *(const v8bf*)wp;                                       \
      a_reg[khkw][1] = *(const v8bf*)(wp + 128);                               \
    }                                                                          \
  }

  // 2560 float4 units per chunk: unit v -> dy=v>>9, c=(v>>4)&31, w4=v&15
#define LOADQ(QQ)                                                              \
  {                                                                            \
    const int cbase = (QQ) * 32;                                               \
    _Pragma("unroll") for (int k = 0; k < 3; ++k) {                            \
      int v = k * 1024 + tid;                                                  \
      if (v < 2560) {                                                          \
        int w4 = v & 15, c = (v >> 4) & 31, dy = v >> 9;                       \
        int y = h0 + dy;                                                       \
        if (y < HW)                                                            \
          xr[k] = *(const f32x4*)(xbase + ((size_t)(cbase + c) * HW + y) * HW +\
                                  w4 * 4);                                     \
        else                                                                   \
          xr[k] = (f32x4){0.f, 0.f, 0.f, 0.f};                                 \
      }                                                                        \
    }                                                                          \
  }

#define WRITEQ(QQ)                                                             \
  {                                                                            \
    char* xd = ((QQ) & 1) ? xb1 : xb0;                                         \
    _Pragma("unroll") for (int k = 0; k < 3; ++k) {                            \
      int v = k * 1024 + tid;                                                  \
      if (v < 2560) {                                                          \
        int w4 = v & 15, c = (v >> 4) & 31, dy = v >> 9;                       \
        _Pragma("unroll") for (int j = 0; j < 4; ++j) {                        \
          int wcol = w4 * 4 + j;                                               \
          int wp_  = wcol >> 1;                                                \
          int bo = ((dy * 33 + wp_) * 128 + (wcol & 1) * 64 + c * 2) ^         \
                   ((wp_ & 7) << 4);                                           \
          *(__bf16*)(xd + bo) = (__bf16)xr[k][j];                              \
        }                                                                      \
      }                                                                        \
    }                                                                          \
  }

  // prologue: fill buffer 0 with chunk 0
  LOADQ(0);
  WRITEQ(0);
  __syncthreads();

  for (int q = 0; q < 8; ++q) {
    A_LOAD(q);               // issued FIRST: compute's vmcnt wait targets these
    if (q < 7) LOADQ(q + 1); // x prefetch stays in flight through compute

    // ---- compute chunk q: 4 khkw K-steps x 8 MFMA, zero VMEM inside ----
    {
      const char* xsb = (q & 1) ? xb1 : xb0;
#pragma unroll
      for (int khkw = 0; khkw < 4; ++khkw) {
        v8bf b[4];
#pragma unroll
        for (int r = 0; r < 2; ++r)
#pragma unroll
          for (int hh = 0; hh < 2; ++hh)
            b[r * 2 + hh] =
                *(const v8bf*)(xsb + boff[khkw] + r * 8448 + hh * 2048);

#pragma unroll
        for (int m = 0; m < 2; ++m)
#pragma unroll
          for (int f = 0; f < 4; ++f)
            acc[m][f] = __builtin_amdgcn_mfma_f32_16x16x32_bf16(
                a_reg[khkw][m], b[f], acc[m][f], 0, 0, 0);
      }
    }

    if (q < 7) {
      WRITEQ(q + 1);     // buf[(q+1)&1] last read at compute(q-1) -> free
      __syncthreads();   // writes visible before compute(q+1)
    }
  }

  // ---- epilogue: D col=lane&15 (pixel), row=(lane>>4)*4+reg (oc) ----
#pragma unroll
  for (int m = 0; m < 2; ++m) {
#pragma unroll
    for (int r = 0; r < 2; ++r) {
      const int h = h0 + 2 * r + ph;
#pragma unroll
      for (int hh = 0; hh < 2; ++hh) {
        const int w = 2 * (hh * 16 + lcol) + pw;
        f32x4 v = acc[m][r * 2 + hh];
        if (h < OHW && w < OHW) {
#pragma unroll
          for (int reg = 0; reg < 4; ++reg) {
            int oc = ocg * 32 + m * 16 + lg * 4 + reg;
            out[((size_t)(n * NOC + oc) * OHW + h) * OHW + w] =
                v[reg] + bias[oc * 4 + kp];
          }
        }
      }
    }
  }
#undef A_LOAD
#undef LOADQ
#undef WRITEQ
}

extern "C" void kernel_launch(void* const* d_in, const int* in_sizes, int n_in,
                              void* d_out, int out_size, void* d_ws, size_t ws_size,
                              hipStream_t stream) {
  const float* x      = (const float*)d_in[0];
  const float* weight = (const float*)d_in[1];
  const float* bias   = (const float*)d_in[2];
  float* out          = (float*)d_out;
  __bf16* Wf          = (__bf16*)d_ws;   // 1 MiB fragment-ordered weights

  wprep<<<512, 256, 0, stream>>>(weight, Wf);
  robin_main<<<dim3(16, 16), 1024, 0, stream>>>(x, Wf, bias, out);
}